// Round 3
// baseline (154.542 us; speedup 1.0000x reference)
//
#include <hip/hip_runtime.h>
#include <hip/hip_bf16.h>

#define N 8192
#define D 200
#define KP 224      // K padded to 7 * 32
#define NSTEP 7
#define NB 64       // 8192 / 128 block-tiles per dim
#define NTRI (NB * (NB + 1) / 2)   // 2080 triangular blocks

typedef __bf16 bf16x8 __attribute__((ext_vector_type(8)));
typedef float f32x4 __attribute__((ext_vector_type(4)));

// ---- prep: cast to bf16 (padded), row norms, labels, zero acc/ticket ----
__global__ __launch_bounds__(256) void prep_kernel(
    const float* __restrict__ x, const int* __restrict__ labels,
    __hip_bfloat16* __restrict__ xb, float* __restrict__ sq,
    int* __restrict__ lab, double* __restrict__ acc, unsigned* __restrict__ ticket) {
  if (blockIdx.x == 0 && threadIdx.x == 0) { *acc = 0.0; *ticket = 0u; }
  int wave = blockIdx.x * 4 + (threadIdx.x >> 6);   // 2048 waves
  int lane = threadIdx.x & 63;
#pragma unroll
  for (int rr = 0; rr < 4; ++rr) {                  // each wave: 4 rows, stride 2048
    int row = wave + rr * 2048;
    const float* xr = x + (size_t)row * D;
    __hip_bfloat16* xbr = xb + (size_t)row * KP;
    float s = 0.f;
#pragma unroll
    for (int c = 0; c < 4; ++c) {
      int k = lane + c * 64;                        // covers 0..255
      float f = (k < D) ? xr[k] : 0.f;
      __hip_bfloat16 h = __float2bfloat16(f);
      float fb = __bfloat162float(h);
      if (k < KP) xbr[k] = h;
      s += fb * fb;                                 // norm of the bf16-rounded row
    }
#pragma unroll
    for (int m = 32; m; m >>= 1) s += __shfl_xor(s, m);
    if (lane == 0) {
      sq[row] = s;
      lab[row] = labels[row];
    }
  }
}

// ------- triangular 128x128 MFMA tile, global->reg prefetch, fused reduce -------
__global__ __launch_bounds__(256) void gram_kernel(
    const __hip_bfloat16* __restrict__ xb, const float* __restrict__ sq,
    const int* __restrict__ lab, double* __restrict__ acc,
    unsigned* __restrict__ ticket, float* __restrict__ out) {
  // decode linear block id -> (bi <= bj) upper-triangular pair
  const int p = blockIdx.x;
  int bi = (int)((129.0f - __builtin_sqrtf(129.0f * 129.0f - 8.0f * (float)p)) * 0.5f);
  while ((bi + 1) * NB - ((bi + 1) * bi) / 2 <= p) ++bi;
  while (bi * NB - (bi * (bi - 1)) / 2 > p) --bi;
  const int bj = bi + (p - (bi * NB - (bi * (bi - 1)) / 2));

  const int t = threadIdx.x;
  const int wid = t >> 6, lane = t & 63;
  const int col = lane & 15, quad = lane >> 4;
  const int waveM = (wid >> 1) * 64, waveN = (wid & 1) * 64;
  const int i0 = bi * 128 + waveM;
  const int j0 = bj * 128 + waveN;

  // row-base pointers computed ONCE; K-steps become imm offsets (<= 448 B)
  const __hip_bfloat16* pa[4];
  const __hip_bfloat16* pb[4];
#pragma unroll
  for (int mi = 0; mi < 4; ++mi)
    pa[mi] = xb + (size_t)(i0 + mi * 16 + col) * KP + quad * 8;
#pragma unroll
  for (int ni = 0; ni < 4; ++ni)
    pb[ni] = xb + (size_t)(j0 + ni * 16 + col) * KP + quad * 8;

  f32x4 acc_r[4][4] = {};
  bf16x8 abuf[2][4], bbuf[2][4];
#pragma unroll
  for (int mi = 0; mi < 4; ++mi) {
    abuf[0][mi] = *(const bf16x8*)(pa[mi]);
    bbuf[0][mi] = *(const bf16x8*)(pb[mi]);
  }
#pragma unroll
  for (int step = 0; step < NSTEP; ++step) {
    const int cur = step & 1, nxt = cur ^ 1;
    if (step < NSTEP - 1) {
#pragma unroll
      for (int mi = 0; mi < 4; ++mi) {
        abuf[nxt][mi] = *(const bf16x8*)(pa[mi] + (step + 1) * 32);
        bbuf[nxt][mi] = *(const bf16x8*)(pb[mi] + (step + 1) * 32);
      }
    }
#pragma unroll
    for (int mi = 0; mi < 4; ++mi)
#pragma unroll
      for (int ni = 0; ni < 4; ++ni)
        acc_r[mi][ni] = __builtin_amdgcn_mfma_f32_16x16x32_bf16(
            abuf[cur][mi], bbuf[cur][ni], acc_r[mi][ni], 0, 0, 0);
  }

  // ---- epilogue: D[m = quad*4 + r][n = col]; accumulate one scalar ----
  int labj[4];
  float sqj[4];
#pragma unroll
  for (int ni = 0; ni < 4; ++ni) {
    int j = j0 + ni * 16 + col;
    labj[ni] = lab[j];
    sqj[ni] = sq[j];
  }
  float rs = 0.f;
#pragma unroll
  for (int mi = 0; mi < 4; ++mi) {
#pragma unroll
    for (int r = 0; r < 4; ++r) {
      int i = i0 + mi * 16 + quad * 4 + r;
      float sqi = sq[i];
      int li = lab[i];
#pragma unroll
      for (int ni = 0; ni < 4; ++ni) {
        int j = j0 + ni * 16 + col;
        float g = acc_r[mi][ni][r];
        float d2 = fmaxf(fmaf(-2.f, g, sqi + sqj[ni]), 0.f);
        float dist = __builtin_sqrtf(d2);
        float c = (li == labj[ni]) ? dist : -dist;
        rs += (i == j) ? 0.f : c;
      }
    }
  }
#pragma unroll
  for (int m = 32; m; m >>= 1) rs += __shfl_xor(rs, m);

  __shared__ double bsum[4];
  if (lane == 0) bsum[wid] = (double)rs * ((bi == bj) ? 1.0 : 2.0);
  __syncthreads();
  if (t == 0) {
    double s = bsum[0] + bsum[1] + bsum[2] + bsum[3];
    atomicAdd(acc, s);
    __threadfence();
    unsigned old = atomicAdd(ticket, 1u);
    if (old == NTRI - 1) {                 // last block: all adds visible
      double tot = atomicAdd(acc, 0.0);    // coherent read of the total
      out[0] = (float)(tot / (double)N);
    }
  }
}

extern "C" void kernel_launch(void* const* d_in, const int* in_sizes, int n_in,
                              void* d_out, int out_size, void* d_ws, size_t ws_size,
                              hipStream_t stream) {
  const float* x = (const float*)d_in[0];
  const int* labels = (const int*)d_in[1];
  char* ws = (char*)d_ws;
  __hip_bfloat16* xb = (__hip_bfloat16*)ws;                        // N*KP*2 = 3.67 MB
  float* sq = (float*)(ws + (size_t)N * KP * 2);                   // N*4
  int* lab = (int*)(ws + (size_t)N * KP * 2 + (size_t)N * 4);      // N*4
  double* acc = (double*)(ws + (size_t)N * KP * 2 + (size_t)N * 8);
  unsigned* ticket = (unsigned*)(ws + (size_t)N * KP * 2 + (size_t)N * 8 + 8);
  float* out = (float*)d_out;

  prep_kernel<<<512, 256, 0, stream>>>(x, labels, xb, sq, lab, acc, ticket);
  gram_kernel<<<NTRI, 256, 0, stream>>>(xb, sq, lab, acc, ticket, out);
}

// Round 4
// 107.402 us; speedup vs baseline: 1.4389x; 1.4389x over previous
//
#include <hip/hip_runtime.h>
#include <hip/hip_bf16.h>
#include <hip/hip_fp8.h>

#define N 8192
#define D 200
#define KP 224      // K padded to 7 * 32
#define NSTEP 7
#define NB 64       // 8192 / 128 block-tiles per dim
#define NTRI (NB * (NB + 1) / 2)   // 2080 triangular blocks
#define NPART (NTRI * 4)           // one partial per wave

typedef float f32x4 __attribute__((ext_vector_type(4)));

// ---- prep: cast to fp8 e4m3 (padded), row norms from fp8-decoded, labels ----
__global__ __launch_bounds__(256) void prep_kernel(
    const float* __restrict__ x, const int* __restrict__ labels,
    unsigned char* __restrict__ xb, float* __restrict__ sq,
    int* __restrict__ lab) {
  int row = blockIdx.x * 4 + (threadIdx.x >> 6);   // one wave per row
  int lane = threadIdx.x & 63;
  const float* xr = x + (size_t)row * D;
  unsigned char* xbr = xb + (size_t)row * KP;
  int k0 = lane * 4;                               // 4 consecutive elems per lane
  float4 f = {0.f, 0.f, 0.f, 0.f};
  if (k0 < D) f = *(const float4*)(xr + k0);       // D=200: lane<50 fully in-bounds
  float s = 0.f;
  unsigned char q[4];
  float ff[4] = {f.x, f.y, f.z, f.w};
#pragma unroll
  for (int c = 0; c < 4; ++c) {
    float v = (k0 + c < D) ? ff[c] : 0.f;
    __hip_fp8_e4m3 h(v);                           // OCP e4m3 RNE
    q[c] = h.__x;
    float fb = (float)h;
    s += fb * fb;                                  // norm of the fp8-rounded row
  }
  if (k0 < KP) *(uchar4*)(xbr + k0) = *(uchar4*)q; // lanes 0..55
#pragma unroll
  for (int m = 32; m; m >>= 1) s += __shfl_xor(s, m);
  if (lane == 0) {
    sq[row] = s;
    lab[row] = labels[row];
  }
}

// ------- triangular 128x128 fp8 MFMA tile, no LDS, scalar-sum epilogue -------
__global__ __launch_bounds__(256) void gram_kernel(
    const unsigned char* __restrict__ xb, const float* __restrict__ sq,
    const int* __restrict__ lab, double* __restrict__ partial) {
  // decode linear block id -> (bi <= bj) upper-triangular pair
  const int p = blockIdx.x;
  int bi = (int)((129.0f - __builtin_sqrtf(129.0f * 129.0f - 8.0f * (float)p)) * 0.5f);
  while ((bi + 1) * NB - ((bi + 1) * bi) / 2 <= p) ++bi;
  while (bi * NB - (bi * (bi - 1)) / 2 > p) --bi;
  const int bj = bi + (p - (bi * NB - (bi * (bi - 1)) / 2));

  const int t = threadIdx.x;
  const int wid = t >> 6, lane = t & 63;
  const int col = lane & 15, quad = lane >> 4;
  const int waveM = (wid >> 1) * 64, waveN = (wid & 1) * 64;
  const int i0 = bi * 128 + waveM;
  const int j0 = bj * 128 + waveN;

  // row-base pointers once; K-steps are imm offsets (<= 192 B)
  const unsigned char* pa[4];
  const unsigned char* pb[4];
#pragma unroll
  for (int mi = 0; mi < 4; ++mi)
    pa[mi] = xb + (size_t)(i0 + mi * 16 + col) * KP + quad * 8;
#pragma unroll
  for (int ni = 0; ni < 4; ++ni)
    pb[ni] = xb + (size_t)(j0 + ni * 16 + col) * KP + quad * 8;

  f32x4 acc[4][4] = {};
#pragma unroll
  for (int step = 0; step < NSTEP; ++step) {
    long a[4], b[4];                               // 8 fp8 per lane = 2 VGPRs
#pragma unroll
    for (int mi = 0; mi < 4; ++mi)
      a[mi] = *(const long*)(pa[mi] + step * 32);
#pragma unroll
    for (int ni = 0; ni < 4; ++ni)
      b[ni] = *(const long*)(pb[ni] + step * 32);
#pragma unroll
    for (int mi = 0; mi < 4; ++mi)
#pragma unroll
      for (int ni = 0; ni < 4; ++ni)
        acc[mi][ni] = __builtin_amdgcn_mfma_f32_16x16x32_fp8_fp8(
            a[mi], b[ni], acc[mi][ni], 0, 0, 0);
  }

  // ---- epilogue: D[m = quad*4 + r][n = col]; accumulate one scalar ----
  int labj[4];
  float sqj[4];
#pragma unroll
  for (int ni = 0; ni < 4; ++ni) {
    int j = j0 + ni * 16 + col;
    labj[ni] = lab[j];
    sqj[ni] = sq[j];
  }
  float rs = 0.f;
#pragma unroll
  for (int mi = 0; mi < 4; ++mi) {
#pragma unroll
    for (int r = 0; r < 4; ++r) {
      int i = i0 + mi * 16 + quad * 4 + r;
      float sqi = sq[i];
      int li = lab[i];
#pragma unroll
      for (int ni = 0; ni < 4; ++ni) {
        int j = j0 + ni * 16 + col;
        float g = acc[mi][ni][r];
        float d2 = fmaxf(fmaf(-2.f, g, sqi + sqj[ni]), 0.f);
        float dist = __builtin_sqrtf(d2);
        float c = (li == labj[ni]) ? dist : -dist;
        rs += (i == j) ? 0.f : c;
      }
    }
  }
#pragma unroll
  for (int m = 32; m; m >>= 1) rs += __shfl_xor(rs, m);
  if (lane == 0) {
    double w = (bi == bj) ? 1.0 : 2.0;   // mirror tile not launched
    partial[p * 4 + wid] = w * (double)rs;
  }
}

// ---------------- final mean ----------------
__global__ __launch_bounds__(256) void reduce_kernel(
    const double* __restrict__ partial, float* __restrict__ out) {
  __shared__ double wsum[4];
  double s = 0.0;
  for (int i = threadIdx.x; i < NPART; i += 256) s += partial[i];
#pragma unroll
  for (int m = 32; m; m >>= 1) s += __shfl_xor(s, m);
  if ((threadIdx.x & 63) == 0) wsum[threadIdx.x >> 6] = s;
  __syncthreads();
  if (threadIdx.x == 0)
    out[0] = (float)((wsum[0] + wsum[1] + wsum[2] + wsum[3]) / (double)N);
}

extern "C" void kernel_launch(void* const* d_in, const int* in_sizes, int n_in,
                              void* d_out, int out_size, void* d_ws, size_t ws_size,
                              hipStream_t stream) {
  const float* x = (const float*)d_in[0];
  const int* labels = (const int*)d_in[1];
  char* ws = (char*)d_ws;
  unsigned char* xb = (unsigned char*)ws;                          // N*KP = 1.83 MB
  float* sq = (float*)(ws + (size_t)N * KP);                       // N*4
  int* lab = (int*)(ws + (size_t)N * KP + (size_t)N * 4);          // N*4
  double* partial = (double*)(ws + (size_t)N * KP + (size_t)N * 8);  // NPART*8
  float* out = (float*)d_out;

  prep_kernel<<<N / 4, 256, 0, stream>>>(x, labels, xb, sq, lab);
  gram_kernel<<<NTRI, 256, 0, stream>>>(xb, sq, lab, partial);
  reduce_kernel<<<1, 256, 0, stream>>>(partial, out);
}

// Round 5
// 88.999 us; speedup vs baseline: 1.7365x; 1.2068x over previous
//
#include <hip/hip_runtime.h>
#include <hip/hip_bf16.h>
#include <hip/hip_fp8.h>

#define N 8192
#define D 200
#define KP 232      // fp8 row stride BYTES: 58 dwords, gcd(58,32)=2 -> <=2-way LDS aliasing
#define NSTEP 7     // 7 * 32 = 224 K actually fed to MFMA
#define NB 64       // 8192 / 128 tiles per dim
#define NTRI (NB * (NB + 1) / 2)   // 2080 triangular blocks
#define NPART (NTRI * 4)
#define PANEL (128 * KP)           // 29696 B, contiguous in global AND in LDS

typedef float f32x4 __attribute__((ext_vector_type(4)));
#define AS3 __attribute__((address_space(3)))
#define AS1 __attribute__((address_space(1)))

// ---- prep: cast to fp8 e4m3 (padded to KP), row norms from fp8-decoded ----
__global__ __launch_bounds__(256) void prep_kernel(
    const float* __restrict__ x, const int* __restrict__ labels,
    unsigned char* __restrict__ xb, float* __restrict__ sq,
    int* __restrict__ lab) {
  int row = blockIdx.x * 4 + (threadIdx.x >> 6);   // one wave per row
  int lane = threadIdx.x & 63;
  const float* xr = x + (size_t)row * D;
  unsigned char* xbr = xb + (size_t)row * KP;
  int k0 = lane * 4;
  float4 f = {0.f, 0.f, 0.f, 0.f};
  if (k0 < D) f = *(const float4*)(xr + k0);       // lane<50 fully in-bounds
  float s = 0.f;
  unsigned char q[4];
  float ff[4] = {f.x, f.y, f.z, f.w};
#pragma unroll
  for (int c = 0; c < 4; ++c) {
    float v = (k0 + c < D) ? ff[c] : 0.f;
    __hip_fp8_e4m3 h(v);                           // OCP e4m3 RNE
    q[c] = h.__x;
    float fb = (float)h;
    s += fb * fb;                                  // norm of the fp8-rounded row
  }
  if (k0 < KP) *(uchar4*)(xbr + k0) = *(uchar4*)q; // lanes 0..57 (56,57 write zeros)
#pragma unroll
  for (int m = 32; m; m >>= 1) s += __shfl_xor(s, m);
  if (lane == 0) {
    sq[row] = s;
    lab[row] = labels[row];
  }
}

// ------- triangular 128x128 fp8 MFMA tile, one-shot LDS staging -------
__global__ __launch_bounds__(256) void gram_kernel(
    const unsigned char* __restrict__ xb, const float* __restrict__ sq,
    const int* __restrict__ lab, double* __restrict__ partial) {
  __shared__ __align__(16) unsigned char sA[PANEL];
  __shared__ __align__(16) unsigned char sB[PANEL];

  // decode linear block id -> (bi <= bj) upper-triangular pair
  const int p = blockIdx.x;
  int bi = (int)((129.0f - __builtin_sqrtf(129.0f * 129.0f - 8.0f * (float)p)) * 0.5f);
  while ((bi + 1) * NB - ((bi + 1) * bi) / 2 <= p) ++bi;
  while (bi * NB - (bi * (bi - 1)) / 2 > p) --bi;
  const int bj = bi + (p - (bi * NB - (bi * (bi - 1)) / 2));
  const bool diag = (bi == bj);

  const int t = threadIdx.x;
  const unsigned char* gA = xb + (size_t)bi * PANEL;
  const unsigned char* gB = xb + (size_t)bj * PANEL;

  // flat 29696-B panel copies: 7 full 4096-B chunks + one 1024-B chunk (wave 0)
#pragma unroll
  for (int c = 0; c < 7; ++c) {
    int off = c * 4096 + t * 16;
    __builtin_amdgcn_global_load_lds((const AS1 void*)(gA + off),
                                     (AS3 void*)(sA + off), 16, 0, 0);
  }
  if (t < 64) {
    int off = 28672 + t * 16;
    __builtin_amdgcn_global_load_lds((const AS1 void*)(gA + off),
                                     (AS3 void*)(sA + off), 16, 0, 0);
  }
  if (!diag) {
#pragma unroll
    for (int c = 0; c < 7; ++c) {
      int off = c * 4096 + t * 16;
      __builtin_amdgcn_global_load_lds((const AS1 void*)(gB + off),
                                       (AS3 void*)(sB + off), 16, 0, 0);
    }
    if (t < 64) {
      int off = 28672 + t * 16;
      __builtin_amdgcn_global_load_lds((const AS1 void*)(gB + off),
                                       (AS3 void*)(sB + off), 16, 0, 0);
    }
  }
  __syncthreads();
  const unsigned char* Bs = diag ? sA : sB;

  const int wid = t >> 6, lane = t & 63;
  const int col = lane & 15, quad = lane >> 4;
  const int waveM = (wid >> 1) * 64, waveN = (wid & 1) * 64;
  const int i0 = bi * 128 + waveM;
  const int j0 = bj * 128 + waveN;

  f32x4 acc[4][4] = {};
#pragma unroll
  for (int step = 0; step < NSTEP; ++step) {
    long a[4], b[4];
#pragma unroll
    for (int mi = 0; mi < 4; ++mi)
      a[mi] = *(const long*)(sA + (waveM + mi * 16 + col) * KP + step * 32 + quad * 8);
#pragma unroll
    for (int ni = 0; ni < 4; ++ni)
      b[ni] = *(const long*)(Bs + (waveN + ni * 16 + col) * KP + step * 32 + quad * 8);
#pragma unroll
    for (int mi = 0; mi < 4; ++mi)
#pragma unroll
      for (int ni = 0; ni < 4; ++ni)
        acc[mi][ni] = __builtin_amdgcn_mfma_f32_16x16x32_fp8_fp8(
            a[mi], b[ni], acc[mi][ni], 0, 0, 0);
  }

  // ---- epilogue: D[m = quad*4 + r][n = col]; accumulate one scalar ----
  int labj[4];
  float sqj[4];
#pragma unroll
  for (int ni = 0; ni < 4; ++ni) {
    int j = j0 + ni * 16 + col;
    labj[ni] = lab[j];
    sqj[ni] = sq[j];
  }
  float rs = 0.f;
  if (!diag) {                                     // 2016/2080 blocks: no i==j test
#pragma unroll
    for (int mi = 0; mi < 4; ++mi) {
#pragma unroll
      for (int r = 0; r < 4; ++r) {
        int i = i0 + mi * 16 + quad * 4 + r;
        float sqi = sq[i];
        int li = lab[i];
#pragma unroll
        for (int ni = 0; ni < 4; ++ni) {
          float g = acc[mi][ni][r];
          float d2 = fmaxf(fmaf(-2.f, g, sqi + sqj[ni]), 0.f);
          float dist = __builtin_amdgcn_sqrtf(d2);
          rs += (li == labj[ni]) ? dist : -dist;
        }
      }
    }
  } else {
#pragma unroll
    for (int mi = 0; mi < 4; ++mi) {
#pragma unroll
      for (int r = 0; r < 4; ++r) {
        int i = i0 + mi * 16 + quad * 4 + r;
        float sqi = sq[i];
        int li = lab[i];
#pragma unroll
        for (int ni = 0; ni < 4; ++ni) {
          int j = j0 + ni * 16 + col;
          float g = acc[mi][ni][r];
          float d2 = fmaxf(fmaf(-2.f, g, sqi + sqj[ni]), 0.f);
          float dist = __builtin_amdgcn_sqrtf(d2);
          float c = (li == labj[ni]) ? dist : -dist;
          rs += (i == j) ? 0.f : c;
        }
      }
    }
  }
#pragma unroll
  for (int m = 32; m; m >>= 1) rs += __shfl_xor(rs, m);
  if (lane == 0) {
    double w = diag ? 1.0 : 2.0;                   // mirror tile not launched
    partial[p * 4 + wid] = w * (double)rs;
  }
}

// ---------------- final mean ----------------
__global__ __launch_bounds__(256) void reduce_kernel(
    const double* __restrict__ partial, float* __restrict__ out) {
  __shared__ double wsum[4];
  double s = 0.0;
  for (int i = threadIdx.x; i < NPART; i += 256) s += partial[i];
#pragma unroll
  for (int m = 32; m; m >>= 1) s += __shfl_xor(s, m);
  if ((threadIdx.x & 63) == 0) wsum[threadIdx.x >> 6] = s;
  __syncthreads();
  if (threadIdx.x == 0)
    out[0] = (float)((wsum[0] + wsum[1] + wsum[2] + wsum[3]) / (double)N);
}

extern "C" void kernel_launch(void* const* d_in, const int* in_sizes, int n_in,
                              void* d_out, int out_size, void* d_ws, size_t ws_size,
                              hipStream_t stream) {
  const float* x = (const float*)d_in[0];
  const int* labels = (const int*)d_in[1];
  char* ws = (char*)d_ws;
  unsigned char* xb = (unsigned char*)ws;                            // N*KP = 1.9 MB
  float* sq = (float*)(ws + (size_t)N * KP);                         // N*4
  int* lab = (int*)(ws + (size_t)N * KP + (size_t)N * 4);            // N*4
  double* partial = (double*)(ws + (size_t)N * KP + (size_t)N * 8);  // NPART*8
  float* out = (float*)d_out;

  prep_kernel<<<N / 4, 256, 0, stream>>>(x, labels, xb, sq, lab);
  gram_kernel<<<NTRI, 256, 0, stream>>>(xb, sq, lab, partial);
  reduce_kernel<<<1, 256, 0, stream>>>(partial, out);
}

// Round 6
// 83.464 us; speedup vs baseline: 1.8516x; 1.0663x over previous
//
#include <hip/hip_runtime.h>
#include <hip/hip_bf16.h>
#include <hip/hip_fp8.h>

#define N 8192
#define D 200
#define KP 232      // fp8 row stride BYTES: 58 dwords, gcd(58,32)=2 -> <=2-way LDS aliasing
#define NSTEP 7     // 7 * 32 = 224 K fed to MFMA
#define NB 64       // 8192 / 128 tiles per dim
#define NBLK 512    // 32 row-pairs x 16 strips; each block: 4-5 tiles
#define NPART (NBLK * 4)
#define PANEL (128 * KP)           // 29696 B, contiguous in global AND in LDS

typedef float f32x4 __attribute__((ext_vector_type(4)));
#define AS3 __attribute__((address_space(3)))
#define AS1 __attribute__((address_space(1)))

// ---- prep: cast to fp8 e4m3 (padded to KP), row norms from fp8-decoded ----
__global__ __launch_bounds__(256) void prep_kernel(
    const float* __restrict__ x, const int* __restrict__ labels,
    unsigned char* __restrict__ xb, float* __restrict__ sq,
    int* __restrict__ lab) {
  int row = blockIdx.x * 4 + (threadIdx.x >> 6);   // one wave per row
  int lane = threadIdx.x & 63;
  const float* xr = x + (size_t)row * D;
  unsigned char* xbr = xb + (size_t)row * KP;
  int k0 = lane * 4;
  float4 f = {0.f, 0.f, 0.f, 0.f};
  if (k0 < D) f = *(const float4*)(xr + k0);       // lane<50 fully in-bounds
  float s = 0.f;
  unsigned char q[4];
  float ff[4] = {f.x, f.y, f.z, f.w};
#pragma unroll
  for (int c = 0; c < 4; ++c) {
    float v = (k0 + c < D) ? ff[c] : 0.f;
    __hip_fp8_e4m3 h(v);                           // OCP e4m3 RNE
    q[c] = h.__x;
    float fb = (float)h;
    s += fb * fb;                                  // norm of the fp8-rounded row
  }
  if (k0 < KP) *(uchar4*)(xbr + k0) = *(uchar4*)q; // lanes 0..57 (56,57 write zeros)
#pragma unroll
  for (int m = 32; m; m >>= 1) s += __shfl_xor(s, m);
  if (lane == 0) {
    sq[row] = s;
    lab[row] = labels[row];
  }
}

// --- multi-tile fp8 MFMA: A-panel reuse, B staging overlapped with epilogue ---
__global__ __launch_bounds__(256) void gram_kernel(
    const unsigned char* __restrict__ xb, const float* __restrict__ sq,
    const int* __restrict__ lab, double* __restrict__ partial) {
  __shared__ __align__(16) unsigned char sA[PANEL];
  __shared__ __align__(16) unsigned char sB[PANEL];

  const int t = threadIdx.x;
  const int b = blockIdx.x;
  const int q = b >> 4, s = b & 15;                // row-pair q / strip s
  const int row2 = 63 - q;
  const int n1 = 64 - q;                           // tiles in row q; row2 has q+1; 65 total

  const int wid = t >> 6, lane = t & 63;
  const int col = lane & 15, quad = lane >> 4;
  const int waveM = (wid >> 1) * 64, waveN = (wid & 1) * 64;

  auto stage = [&](const unsigned char* g, unsigned char* sh) {
#pragma unroll
    for (int c = 0; c < 7; ++c) {
      int off = c * 4096 + t * 16;
      __builtin_amdgcn_global_load_lds((const AS1 void*)(g + off),
                                       (AS3 void*)(sh + off), 16, 0, 0);
    }
    if (t < 64) {
      int off = 28672 + t * 16;
      __builtin_amdgcn_global_load_lds((const AS1 void*)(g + off),
                                       (AS3 void*)(sh + off), 16, 0, 0);
    }
  };

  int idx = s;                                     // strided walk: s, s+16, ... < 65
  int bi = (idx < n1) ? q : row2;
  int bj = (idx < n1) ? q + idx : row2 + (idx - n1);
  stage(xb + (size_t)bi * PANEL, sA);
  stage(xb + (size_t)bj * PANEL, sB);
  __syncthreads();

  float tot = 0.f;
  while (true) {
    // ---- K-loop on (bi, bj) ----
    f32x4 acc[4][4] = {};
#pragma unroll
    for (int step = 0; step < NSTEP; ++step) {
      long a[4], bf[4];
#pragma unroll
      for (int mi = 0; mi < 4; ++mi)
        a[mi] = *(const long*)(sA + (waveM + mi * 16 + col) * KP + step * 32 + quad * 8);
#pragma unroll
      for (int ni = 0; ni < 4; ++ni)
        bf[ni] = *(const long*)(sB + (waveN + ni * 16 + col) * KP + step * 32 + quad * 8);
#pragma unroll
      for (int mi = 0; mi < 4; ++mi)
#pragma unroll
        for (int ni = 0; ni < 4; ++ni)
          acc[mi][ni] = __builtin_amdgcn_mfma_f32_16x16x32_fp8_fp8(
              a[mi], bf[ni], acc[mi][ni], 0, 0, 0);
    }
    __syncthreads();                               // all waves done reading sA/sB

    // ---- issue next tile's staging BEFORE the epilogue (overlap) ----
    const int nidx = idx + 16;
    const bool more = (nidx < 65);
    int nbi = 0, nbj = 0;
    if (more) {
      nbi = (nidx < n1) ? q : row2;
      nbj = (nidx < n1) ? q + nidx : row2 + (nidx - n1);
      if (nbi != bi) stage(xb + (size_t)nbi * PANEL, sA);   // rare: row switch
      stage(xb + (size_t)nbj * PANEL, sB);
    }

    // ---- epilogue (overlaps staging): D[m = quad*4 + r][n = col] ----
    const int i0 = bi * 128 + waveM, j0 = bj * 128 + waveN;
    int labj[4];
    float sqj[4];
#pragma unroll
    for (int ni = 0; ni < 4; ++ni) {
      int j = j0 + ni * 16 + col;
      labj[ni] = lab[j];
      sqj[ni] = sq[j];
    }
    float rs = 0.f;
    if (bi != bj) {
#pragma unroll
      for (int mi = 0; mi < 4; ++mi) {
#pragma unroll
        for (int r = 0; r < 4; ++r) {
          int i = i0 + mi * 16 + quad * 4 + r;
          float sqi = sq[i];
          int li = lab[i];
#pragma unroll
          for (int ni = 0; ni < 4; ++ni) {
            float g = acc[mi][ni][r];
            float d2 = fmaxf(fmaf(-2.f, g, sqi + sqj[ni]), 0.f);
            float dist = __builtin_amdgcn_sqrtf(d2);
            rs += (li == labj[ni]) ? dist : -dist;
          }
        }
      }
      tot += 2.f * rs;                             // mirror tile not launched
    } else {
#pragma unroll
      for (int mi = 0; mi < 4; ++mi) {
#pragma unroll
        for (int r = 0; r < 4; ++r) {
          int i = i0 + mi * 16 + quad * 4 + r;
          float sqi = sq[i];
          int li = lab[i];
#pragma unroll
          for (int ni = 0; ni < 4; ++ni) {
            int j = j0 + ni * 16 + col;
            float g = acc[mi][ni][r];
            float d2 = fmaxf(fmaf(-2.f, g, sqi + sqj[ni]), 0.f);
            float dist = __builtin_amdgcn_sqrtf(d2);
            float c = (li == labj[ni]) ? dist : -dist;
            rs += (i == j) ? 0.f : c;
          }
        }
      }
      tot += rs;
    }

    if (!more) break;
    bi = nbi; bj = nbj; idx = nidx;
    __syncthreads();                               // staging (vmcnt) drained here
  }

#pragma unroll
  for (int m = 32; m; m >>= 1) tot += __shfl_xor(tot, m);
  if (lane == 0) partial[b * 4 + wid] = (double)tot;
}

// ---------------- final mean ----------------
__global__ __launch_bounds__(256) void reduce_kernel(
    const double* __restrict__ partial, float* __restrict__ out) {
  __shared__ double wsum[4];
  double s = 0.0;
  for (int i = threadIdx.x; i < NPART; i += 256) s += partial[i];
#pragma unroll
  for (int m = 32; m; m >>= 1) s += __shfl_xor(s, m);
  if ((threadIdx.x & 63) == 0) wsum[threadIdx.x >> 6] = s;
  __syncthreads();
  if (threadIdx.x == 0)
    out[0] = (float)((wsum[0] + wsum[1] + wsum[2] + wsum[3]) / (double)N);
}

extern "C" void kernel_launch(void* const* d_in, const int* in_sizes, int n_in,
                              void* d_out, int out_size, void* d_ws, size_t ws_size,
                              hipStream_t stream) {
  const float* x = (const float*)d_in[0];
  const int* labels = (const int*)d_in[1];
  char* ws = (char*)d_ws;
  unsigned char* xb = (unsigned char*)ws;                            // N*KP = 1.9 MB
  float* sq = (float*)(ws + (size_t)N * KP);                         // N*4
  int* lab = (int*)(ws + (size_t)N * KP + (size_t)N * 4);            // N*4
  double* partial = (double*)(ws + (size_t)N * KP + (size_t)N * 8);  // NPART*8
  float* out = (float*)d_out;

  prep_kernel<<<N / 4, 256, 0, stream>>>(x, labels, xb, sq, lab);
  gram_kernel<<<NBLK, 256, 0, stream>>>(xb, sq, lab, partial);
  reduce_kernel<<<1, 256, 0, stream>>>(partial, out);
}